// Round 9
// baseline (53.537 us; speedup 1.0000x reference)
//
#include <hip/hip_runtime.h>

// N=16, C_X=512, C_W=32, groups=16, H=W=out_h=out_w=64, K=3, PAD=1.
constexpr int NB   = 16;
constexpr int CX   = 512;
constexpr int CW   = 32;
constexpr int GRP  = 16;   // CX / CW
constexpr int HW   = 64;
constexpr int PIX  = HW * HW; // 4096

typedef float f32x4 __attribute__((ext_vector_type(4)));

// Thread <-> (n, c, g, oh-PAIR, quad of 4 ow): computes TWO output rows,
// loading 4 input rows (rows oh0 & oh0+1 share q1,q2 -> 2 loads/output row
// instead of 3). Block = 256 threads = one (n,c,oh-pair) x 16 groups x 16
// quads. Weights for both rows staged in LDS [9][2][64] (4.5 KB, broadcast
// reads). Output stores non-temporal (write-once; preserves L3 read residency).
__global__ __launch_bounds__(256, 8) void agg_kernel(
    const float* __restrict__ in,   // [16][512][64][64]
    const float* __restrict__ wt,   // [16][32][9][4096]
    float* __restrict__ out)        // [16][512][64][64]
{
    __shared__ float wlds[9][2][64];

    // Chunked XCD swizzle: 16384 blocks, bijective (16384 % 8 == 0).
    int bid = blockIdx.x;
    int wg  = (bid & 7) * (16384 / 8) + (bid >> 3);

    int ohp = wg & 31;          // oh pair: rows oh0, oh0+1
    int c   = (wg >> 5) & 31;
    int n   = wg >> 10;
    int oh0 = ohp * 2;

    int tid = threadIdx.x;
    int q   = tid & 15;   // quad: pixels x = 4q .. 4q+3
    int g   = tid >> 4;   // group 0..15

    // ---- Stage weights: wlds[kk][r][col] = wt[n][c][kk][(oh0+r)*64+col].
    const float* wbase = wt + ((size_t)(n * CW + c) * 9) * PIX + oh0 * HW;
    {
        int f   = tid * 4;               // 1152 floats total = 288 float4
        int kk  = f >> 7;
        int r   = (f >> 6) & 1;
        int col = f & 63;
        *(float4*)(&wlds[kk][r][col]) =
            *(const float4*)(wbase + (size_t)kk * PIX + r * HW + col);
        if (tid < 32) {
            int f2   = 1024 + tid * 4;
            int kk2  = f2 >> 7;          // == 8
            int r2   = (f2 >> 6) & 1;
            int col2 = f2 & 63;
            *(float4*)(&wlds[kk2][r2][col2]) =
                *(const float4*)(wbase + (size_t)kk2 * PIX + r2 * HW + col2);
        }
    }
    __syncthreads();

    int x = q * 4;

    // Masks. Row oh0's top tap OOB only if oh0==0; row oh0+1's bottom tap OOB
    // only if oh0==62. q==0/15 masks also kill cross-group shuffle garbage.
    float mt = (oh0 == 0)  ? 0.f : 1.f;
    float mb = (oh0 == 62) ? 0.f : 1.f;
    float ml = (q == 0)    ? 0.f : 1.f;
    float mr = (q == 15)   ? 0.f : 1.f;

    const int ra = (oh0 == 0  ? 0  : oh0 - 1) * HW;  // clamped top row
    const int rb = oh0 * HW;
    const int rc = (oh0 + 1) * HW;
    const int rd = (oh0 == 62 ? 63 : oh0 + 2) * HW;  // clamped bottom row

    const float* ip = in + ((size_t)(n * CX) + (size_t)(g * CW + c)) * PIX;

    float4 q0 = *(const float4*)(ip + ra + x);
    float4 q1 = *(const float4*)(ip + rb + x);
    float4 q2 = *(const float4*)(ip + rc + x);
    float4 q3 = *(const float4*)(ip + rd + x);

    // Halo pixels from neighbor lanes.
    float l0 = __shfl_up(q0.w, 1), h0 = __shfl_down(q0.x, 1);
    float l1 = __shfl_up(q1.w, 1), h1 = __shfl_down(q1.x, 1);
    float l2 = __shfl_up(q2.w, 1), h2 = __shfl_down(q2.x, 1);
    float l3 = __shfl_up(q3.w, 1), h3 = __shfl_down(q3.x, 1);

    // Apply masks to inputs.
    q0.x *= mt; q0.y *= mt; q0.z *= mt; q0.w *= mt;
    q3.x *= mb; q3.y *= mb; q3.z *= mb; q3.w *= mb;
    l0 *= ml * mt; h0 *= mr * mt;
    l1 *= ml;      h1 *= mr;
    l2 *= ml;      h2 *= mr;
    l3 *= ml * mb; h3 *= mr * mb;

    // ---- Row 0 (output row oh0): taps (l0,q0,h0 / l1,q1,h1 / l2,q2,h2).
    {
        float4 w0 = *(const float4*)&wlds[0][0][x];
        float4 w1 = *(const float4*)&wlds[1][0][x];
        float4 w2 = *(const float4*)&wlds[2][0][x];
        float4 w3 = *(const float4*)&wlds[3][0][x];
        float4 w4 = *(const float4*)&wlds[4][0][x];
        float4 w5 = *(const float4*)&wlds[5][0][x];
        float4 w6 = *(const float4*)&wlds[6][0][x];
        float4 w7 = *(const float4*)&wlds[7][0][x];
        float4 w8 = *(const float4*)&wlds[8][0][x];

        float4 acc;
        acc.x = w0.x * l0;
        acc.y = w0.y * q0.x;
        acc.z = w0.z * q0.y;
        acc.w = w0.w * q0.z;
        acc.x = fmaf(w1.x, q0.x, acc.x);
        acc.y = fmaf(w1.y, q0.y, acc.y);
        acc.z = fmaf(w1.z, q0.z, acc.z);
        acc.w = fmaf(w1.w, q0.w, acc.w);
        acc.x = fmaf(w2.x, q0.y, acc.x);
        acc.y = fmaf(w2.y, q0.z, acc.y);
        acc.z = fmaf(w2.z, q0.w, acc.z);
        acc.w = fmaf(w2.w, h0,   acc.w);
        acc.x = fmaf(w3.x, l1,   acc.x);
        acc.y = fmaf(w3.y, q1.x, acc.y);
        acc.z = fmaf(w3.z, q1.y, acc.z);
        acc.w = fmaf(w3.w, q1.z, acc.w);
        acc.x = fmaf(w4.x, q1.x, acc.x);
        acc.y = fmaf(w4.y, q1.y, acc.y);
        acc.z = fmaf(w4.z, q1.z, acc.z);
        acc.w = fmaf(w4.w, q1.w, acc.w);
        acc.x = fmaf(w5.x, q1.y, acc.x);
        acc.y = fmaf(w5.y, q1.z, acc.y);
        acc.z = fmaf(w5.z, q1.w, acc.z);
        acc.w = fmaf(w5.w, h1,   acc.w);
        acc.x = fmaf(w6.x, l2,   acc.x);
        acc.y = fmaf(w6.y, q2.x, acc.y);
        acc.z = fmaf(w6.z, q2.y, acc.z);
        acc.w = fmaf(w6.w, q2.z, acc.w);
        acc.x = fmaf(w7.x, q2.x, acc.x);
        acc.y = fmaf(w7.y, q2.y, acc.y);
        acc.z = fmaf(w7.z, q2.z, acc.z);
        acc.w = fmaf(w7.w, q2.w, acc.w);
        acc.x = fmaf(w8.x, q2.y, acc.x);
        acc.y = fmaf(w8.y, q2.z, acc.y);
        acc.z = fmaf(w8.z, q2.w, acc.z);
        acc.w = fmaf(w8.w, h2,   acc.w);

        float* op = out + ((size_t)(n * CX) + (size_t)(g * CW + c)) * PIX + rb + x;
        f32x4 nv = { acc.x, acc.y, acc.z, acc.w };
        __builtin_nontemporal_store(nv, (f32x4*)op);
    }

    // ---- Row 1 (output row oh0+1): taps (l1,q1,h1 / l2,q2,h2 / l3,q3,h3).
    {
        float4 w0 = *(const float4*)&wlds[0][1][x];
        float4 w1 = *(const float4*)&wlds[1][1][x];
        float4 w2 = *(const float4*)&wlds[2][1][x];
        float4 w3 = *(const float4*)&wlds[3][1][x];
        float4 w4 = *(const float4*)&wlds[4][1][x];
        float4 w5 = *(const float4*)&wlds[5][1][x];
        float4 w6 = *(const float4*)&wlds[6][1][x];
        float4 w7 = *(const float4*)&wlds[7][1][x];
        float4 w8 = *(const float4*)&wlds[8][1][x];

        float4 acc;
        acc.x = w0.x * l1;
        acc.y = w0.y * q1.x;
        acc.z = w0.z * q1.y;
        acc.w = w0.w * q1.z;
        acc.x = fmaf(w1.x, q1.x, acc.x);
        acc.y = fmaf(w1.y, q1.y, acc.y);
        acc.z = fmaf(w1.z, q1.z, acc.z);
        acc.w = fmaf(w1.w, q1.w, acc.w);
        acc.x = fmaf(w2.x, q1.y, acc.x);
        acc.y = fmaf(w2.y, q1.z, acc.y);
        acc.z = fmaf(w2.z, q1.w, acc.z);
        acc.w = fmaf(w2.w, h1,   acc.w);
        acc.x = fmaf(w3.x, l2,   acc.x);
        acc.y = fmaf(w3.y, q2.x, acc.y);
        acc.z = fmaf(w3.z, q2.y, acc.z);
        acc.w = fmaf(w3.w, q2.z, acc.w);
        acc.x = fmaf(w4.x, q2.x, acc.x);
        acc.y = fmaf(w4.y, q2.y, acc.y);
        acc.z = fmaf(w4.z, q2.z, acc.z);
        acc.w = fmaf(w4.w, q2.w, acc.w);
        acc.x = fmaf(w5.x, q2.y, acc.x);
        acc.y = fmaf(w5.y, q2.z, acc.y);
        acc.z = fmaf(w5.z, q2.w, acc.z);
        acc.w = fmaf(w5.w, h2,   acc.w);
        acc.x = fmaf(w6.x, l3,   acc.x);
        acc.y = fmaf(w6.y, q3.x, acc.y);
        acc.z = fmaf(w6.z, q3.y, acc.z);
        acc.w = fmaf(w6.w, q3.z, acc.w);
        acc.x = fmaf(w7.x, q3.x, acc.x);
        acc.y = fmaf(w7.y, q3.y, acc.y);
        acc.z = fmaf(w7.z, q3.z, acc.z);
        acc.w = fmaf(w7.w, q3.w, acc.w);
        acc.x = fmaf(w8.x, q3.y, acc.x);
        acc.y = fmaf(w8.y, q3.z, acc.y);
        acc.z = fmaf(w8.z, q3.w, acc.z);
        acc.w = fmaf(w8.w, h3,   acc.w);

        float* op = out + ((size_t)(n * CX) + (size_t)(g * CW + c)) * PIX + rc + x;
        f32x4 nv = { acc.x, acc.y, acc.z, acc.w };
        __builtin_nontemporal_store(nv, (f32x4*)op);
    }
}

extern "C" void kernel_launch(void* const* d_in, const int* in_sizes, int n_in,
                              void* d_out, int out_size, void* d_ws, size_t ws_size,
                              hipStream_t stream) {
    const float* in = (const float*)d_in[0];   // (16, 512, 64, 64) f32
    const float* wt = (const float*)d_in[1];   // (16, 32, 9, 4096) f32
    float* out = (float*)d_out;                // (16, 512, 64, 64) f32

    const int grid  = NB * CW * (HW / 2);  // 16384 blocks
    const int block = 256;                 // 16 groups x 16 quads
    agg_kernel<<<grid, block, 0, stream>>>(in, wt, out);
}